// Round 7
// baseline (1220.625 us; speedup 1.0000x reference)
//
#include <hip/hip_runtime.h>
#include <hip/hip_bf16.h>
#include <math.h>

#define N_NODES 50000
#define N_EDGES 400000
#define N_GRAPHS 2500
#define D 128
#define D3 384
#define N_RBF 20
#define R_CUT 5.0f
#define PI_F 3.14159265358979f
#define NCH 98   // ceil(50000/512)
#define GEB 16   // gate edge batch (one MFMA row-block)
#define GS 392   // gate_lds row stride (shorts): 256 pair + 128 plane + 8 pad

typedef __attribute__((ext_vector_type(8))) short bf16x8;
typedef __attribute__((ext_vector_type(4))) float f32x4;

__device__ __forceinline__ float silu_f(float x) {
    return x / (1.0f + __expf(-x));
}
__device__ __forceinline__ short f2bf(float x) {
    union { float f; unsigned u; } v; v.f = x;
    unsigned r = (v.u + 0x7FFFu + ((v.u >> 16) & 1u)) >> 16;
    return (short)r;
}
__device__ __forceinline__ float bf2f(short x) {
    union { unsigned u; float f; } v; v.u = ((unsigned)(unsigned short)x) << 16;
    return v.f;
}

// ---------------- all weight packs in ONE dispatch ----------------
#define MAXJOBS 19
struct PackJobs {
    const float* W[MAXJOBS];
    short* P[MAXJOBS];
    int K[MAXJOBS];
    int N[MAXJOBS];
    int boff[MAXJOBS + 1];
    int njobs;
};
__global__ void k_packall(PackJobs jobs) {
    int b = blockIdx.x;
    int j = 0;
    while (j + 1 < jobs.njobs && b >= jobs.boff[j + 1]) ++j;
    int t = (b - jobs.boff[j]) * 256 + threadIdx.x;
    int K = jobs.K[j], N = jobs.N[j];
    int NKT = K / 32;
    int total = (N / 16) * NKT * 64;
    if (t >= total) return;
    const float* W = jobs.W[j];
    short* P = jobs.P[j];
    int lane = t & 63;
    int kt = (t >> 6) % NKT;
    int nt = (t >> 6) / NKT;
    int k0 = kt * 32 + (lane >> 4) * 8;
    int col = nt * 16 + (lane & 15);
    #pragma unroll
    for (int q = 0; q < 8; ++q)
        P[(size_t)t * 8 + q] = f2bf(W[(size_t)(k0 + q) * N + col]);
}

// pack [rbf_w(20 rows); rbf_b(1 row); zeros] -> frags, 3 blocks in one dispatch
__global__ void k_packrbf(const float* __restrict__ rbf_w, const float* __restrict__ rbf_b,
                          short* __restrict__ P) {
    int t = blockIdx.x * 256 + threadIdx.x;
    if (t >= 3 * 1536) return;
    int i = t / 1536;
    int r = t - i * 1536;        // nt*64 + lane
    int lane = r & 63;
    int nt = r >> 6;
    int col = nt * 16 + (lane & 15);
    int k0 = (lane >> 4) * 8;
    const float* W = rbf_w + (size_t)i * N_RBF * D3;
    const float* B = rbf_b + (size_t)i * D3;
    short* out = P + (size_t)i * 12288 + (size_t)r * 8;
    #pragma unroll
    for (int q = 0; q < 8; ++q) {
        int k = k0 + q;
        float v = (k < N_RBF) ? W[(size_t)k * D3 + col] : ((k == N_RBF) ? B[col] : 0.0f);
        out[q] = f2bf(v);
    }
}

// ---------------- generic MFMA GEMM ----------------
// AMODE: 0 = A bf16 ; 1 = A f32 ; 3 = A1 = Vv bf16 (on-the-fly V_norm, k<128) + A2 f32 (k>=128)
// CMODE: 0 = row-major ; 1 = edge-gather pair-interleave (cols<256 -> pairs, >=256 plane)
template<int K, int N, bool SILU, int AMODE, int CMODE>
__global__ __launch_bounds__(256) void k_gemm(const void* __restrict__ Aptr,
                                              const void* __restrict__ A2ptr,
                                              const short* __restrict__ Bp,
                                              const float* __restrict__ bias,
                                              short* __restrict__ Cbf, int M) {
    constexpr int NKT = K / 32, NNT = N / 16;
    int lane = threadIdx.x & 63, wv = threadIdx.x >> 6;
    int tile = blockIdx.x * 4 + wv;
    if (tile * 16 >= M) return;
    int arow = tile * 16 + (lane & 15);
    int kgrp = (lane >> 4) * 8;

    bf16x8 a[NKT];
    if (AMODE == 0) {
        const short* A = (const short*)Aptr + (size_t)arow * K + kgrp;
        #pragma unroll
        for (int kt = 0; kt < NKT; ++kt) a[kt] = *(const bf16x8*)(A + kt * 32);
    } else if (AMODE == 1) {
        const float* A = (const float*)Aptr + (size_t)arow * K + kgrp;
        #pragma unroll
        for (int kt = 0; kt < NKT; ++kt)
            #pragma unroll
            for (int j = 0; j < 8; ++j) a[kt][j] = f2bf(A[kt * 32 + j]);
    } else {
        // AMODE 3: first 128 k = V_norm from Vv[(n*3+d)*128+k] (node-contiguous: n*384)
        const short* A1 = (const short*)Aptr + (size_t)arow * D3 + kgrp;
        const float* A2 = (const float*)A2ptr + (size_t)arow * 128 + kgrp;
        #pragma unroll
        for (int kt = 0; kt < 4 && kt < NKT; ++kt) {
            bf16x8 v0 = *(const bf16x8*)(A1 + kt * 32);
            bf16x8 v1 = *(const bf16x8*)(A1 + kt * 32 + 128);
            bf16x8 v2 = *(const bf16x8*)(A1 + kt * 32 + 256);
            #pragma unroll
            for (int j = 0; j < 8; ++j) {
                float f0 = bf2f(v0[j]), f1 = bf2f(v1[j]), f2 = bf2f(v2[j]);
                a[kt][j] = f2bf(sqrtf(f0 * f0 + f1 * f1 + f2 * f2));
            }
        }
        #pragma unroll
        for (int kt = 4; kt < NKT; ++kt)
            #pragma unroll
            for (int j = 0; j < 8; ++j) a[kt][j] = f2bf(A2[(kt - 4) * 32 + j]);
    }

    int crow0 = tile * 16 + (lane >> 4) * 4;
    int ccol = lane & 15;
    const bf16x8* Bv = (const bf16x8*)Bp;
    #pragma unroll
    for (int nt = 0; nt < NNT; ++nt) {
        f32x4 acc = {0.f, 0.f, 0.f, 0.f};
        #pragma unroll
        for (int kt = 0; kt < NKT; ++kt) {
            bf16x8 b = Bv[(nt * NKT + kt) * 64 + lane];
            acc = __builtin_amdgcn_mfma_f32_16x16x32_bf16(a[kt], b, acc, 0, 0, 0);
        }
        int col = nt * 16 + ccol;
        float bs = bias ? bias[col] : 0.0f;
        int oidx = (CMODE == 1) ? (col < 256 ? (((col & 127) << 1) | (col >> 7)) : col) : col;
        #pragma unroll
        for (int j = 0; j < 4; ++j) {
            float v = acc[j] + bs;
            if (SILU) v = silu_f(v);
            Cbf[(size_t)(crow0 + j) * N + oidx] = f2bf(v);
        }
    }
}

// ---------------- fused U/V GEMM: one A read, two C outputs ----------------
__global__ __launch_bounds__(256) void k_gemmUV(const short* __restrict__ A,
                                                const short* __restrict__ Bp,
                                                short* __restrict__ Cu,
                                                short* __restrict__ Cv, int M) {
    int lane = threadIdx.x & 63, wv = threadIdx.x >> 6;
    int tile = blockIdx.x * 4 + wv;
    if (tile * 16 >= M) return;
    int arow = tile * 16 + (lane & 15);
    int kgrp = (lane >> 4) * 8;
    const short* Ar = A + (size_t)arow * 128 + kgrp;
    bf16x8 a[4];
    #pragma unroll
    for (int kt = 0; kt < 4; ++kt) a[kt] = *(const bf16x8*)(Ar + kt * 32);
    int crow0 = tile * 16 + (lane >> 4) * 4;
    int ccol = lane & 15;
    const bf16x8* Bv = (const bf16x8*)Bp;
    #pragma unroll
    for (int nt = 0; nt < 16; ++nt) {
        f32x4 acc = {0.f, 0.f, 0.f, 0.f};
        #pragma unroll
        for (int kt = 0; kt < 4; ++kt)
            acc = __builtin_amdgcn_mfma_f32_16x16x32_bf16(a[kt], Bv[(nt * 4 + kt) * 64 + lane], acc, 0, 0, 0);
        int col = nt * 16 + ccol;
        short* C = (col < 128) ? Cu : Cv;
        int cc = col & 127;
        #pragma unroll
        for (int j = 0; j < 4; ++j)
            C[(size_t)(crow0 + j) * 128 + cc] = f2bf(acc[j]);
    }
}

// ---------------- fused upd_w2 GEMM + gated apply ----------------
__global__ __launch_bounds__(256) void k_w2apply(const short* __restrict__ A,
                                                 const short* __restrict__ Bp,
                                                 const float* __restrict__ b2,
                                                 const short* __restrict__ Uv,
                                                 const short* __restrict__ Vv,
                                                 float* __restrict__ s,
                                                 short* __restrict__ v, int M) {
    int lane = threadIdx.x & 63, wv = threadIdx.x >> 6;
    int tile = blockIdx.x * 4 + wv;
    if (tile * 16 >= M) return;
    int arow = tile * 16 + (lane & 15);
    int kgrp = (lane >> 4) * 8;
    const short* Ar = A + (size_t)arow * 128 + kgrp;
    bf16x8 a[4];
    #pragma unroll
    for (int kt = 0; kt < 4; ++kt) a[kt] = *(const bf16x8*)(Ar + kt * 32);
    int crow0 = tile * 16 + (lane >> 4) * 4;
    int ccol = lane & 15;
    const bf16x8* Bv = (const bf16x8*)Bp;
    #pragma unroll
    for (int t = 0; t < 8; ++t) {
        f32x4 accA = {0.f, 0.f, 0.f, 0.f};
        f32x4 accS = {0.f, 0.f, 0.f, 0.f};
        f32x4 accB = {0.f, 0.f, 0.f, 0.f};
        #pragma unroll
        for (int kt = 0; kt < 4; ++kt) {
            accA = __builtin_amdgcn_mfma_f32_16x16x32_bf16(a[kt], Bv[(t * 4 + kt) * 64 + lane], accA, 0, 0, 0);
            accS = __builtin_amdgcn_mfma_f32_16x16x32_bf16(a[kt], Bv[((t + 8) * 4 + kt) * 64 + lane], accS, 0, 0, 0);
            accB = __builtin_amdgcn_mfma_f32_16x16x32_bf16(a[kt], Bv[((t + 16) * 4 + kt) * 64 + lane], accB, 0, 0, 0);
        }
        int c = t * 16 + ccol;
        float bA = b2[c], bS = b2[128 + c], bB = b2[256 + c];
        #pragma unroll
        for (int j = 0; j < 4; ++j) {
            int n = crow0 + j;
            float avv = accA[j] + bA;
            float asv = accS[j] + bS;
            float ass = accB[j] + bB;
            const short* Un = Uv + (size_t)n * D3;
            const short* Vn = Vv + (size_t)n * D3;
            short* vn = v + (size_t)n * D3;
            float scal = 0.f;
            #pragma unroll
            for (int d = 0; d < 3; ++d) {
                float u = bf2f(Un[d * 128 + c]);
                float vv = bf2f(Vn[d * 128 + c]);
                scal += u * vv;
                vn[d * 128 + c] = f2bf(bf2f(vn[d * 128 + c]) + avv * u);
            }
            s[(size_t)n * D + c] += scal * asv + ass;
        }
    }
}

// ---------------- embed ----------------
__global__ void k_embed(const int* __restrict__ z, const float* __restrict__ emb,
                        float* __restrict__ s) {
    int i = blockIdx.x * blockDim.x + threadIdx.x;
    if (i < N_NODES * D) {
        int n = i >> 7, c = i & 127;
        s[i] = emb[z[n] * D + c];
    }
}

// ---------------- edge-sort precompute ----------------
__global__ void k_hist(const int* __restrict__ edges, int* __restrict__ cnt) {
    int e = blockIdx.x * 256 + threadIdx.x;
    if (e < N_EDGES) atomicAdd(&cnt[edges[2 * e]], 1);
}

__global__ void k_scan1(const int* __restrict__ cnt, int* __restrict__ csum) {
    int t = threadIdx.x;                  // 512 threads
    int g = blockIdx.x * 512 + t;
    int v = (g < N_NODES) ? cnt[g] : 0;
    #pragma unroll
    for (int off = 32; off > 0; off >>= 1) v += __shfl_down(v, off, 64);
    __shared__ int ws[8];
    if ((t & 63) == 0) ws[t >> 6] = v;
    __syncthreads();
    if (t == 0) {
        int sum = 0;
        #pragma unroll
        for (int i = 0; i < 8; ++i) sum += ws[i];
        csum[blockIdx.x] = sum;
    }
}

__global__ void k_scan2(const int* __restrict__ csum, int* __restrict__ cbase) {
    if (threadIdx.x == 0 && blockIdx.x == 0) {
        int s = 0;
        for (int i = 0; i < NCH; ++i) { cbase[i] = s; s += csum[i]; }
    }
}

__global__ void k_scan3(const int* __restrict__ cnt, const int* __restrict__ cbase,
                        int* __restrict__ rowptr) {
    __shared__ int buf[512];
    int t = threadIdx.x;
    int g = blockIdx.x * 512 + t;
    int orig = (g < N_NODES) ? cnt[g] : 0;
    buf[t] = orig;
    __syncthreads();
    for (int off = 1; off < 512; off <<= 1) {
        int v = (t >= off) ? buf[t - off] : 0;
        __syncthreads();
        buf[t] += v;
        __syncthreads();
    }
    if (g < N_NODES) rowptr[g] = cbase[blockIdx.x] + buf[t] - orig;
    if (g == 0 && blockIdx.x == 0) rowptr[N_NODES] = N_EDGES;
}

// scatter edges into dst-sorted order
// per edge erbf[32]: 0-19 rbf*fc, 20 fc, 21-23 rhat (bf16), 24-31 zero
__global__ void k_scatter(const int* __restrict__ edges, const float* __restrict__ r_ij,
                          const float* __restrict__ rhat, const int* __restrict__ rowptr,
                          int* __restrict__ cursor, int* __restrict__ esrc,
                          short* __restrict__ erbf) {
    int e = blockIdx.x * 256 + threadIdx.x;
    if (e >= N_EDGES) return;
    int dst = edges[2 * e], src = edges[2 * e + 1];
    int p = rowptr[dst] + atomicAdd(&cursor[dst], 1);
    esrc[p] = src;
    float r = r_ij[e];
    float fc = (r <= R_CUT) ? 0.5f * (cosf(PI_F * r / R_CUT) + 1.0f) : 0.0f;
    float inv_r = 1.0f / r;
    short rec[32];
    #pragma unroll
    for (int k = 0; k < N_RBF; ++k)
        rec[k] = f2bf(sinf((float)(k + 1) * (PI_F / R_CUT) * r) * inv_r * fc);
    rec[20] = f2bf(fc);
    rec[21] = f2bf(rhat[3 * e]);
    rec[22] = f2bf(rhat[3 * e + 1]);
    rec[23] = f2bf(rhat[3 * e + 2]);
    #pragma unroll
    for (int k = 24; k < 32; ++k) rec[k] = 0;
    short* out = erbf + (size_t)p * 32;
    #pragma unroll
    for (int k = 0; k < 32; ++k) out[k] = rec[k];
}

// ---------------- edge kernel: MFMA gates + gather, one node per 128-thread block ----------------
// spass is pair-interleaved: [2c]=col c (dv gate src), [2c+1]=col 128+c, [256+c]=col 256+c
__global__ __launch_bounds__(128, 4) void k_edge3(
    const int* __restrict__ rowptr, const int* __restrict__ esrc,
    const short* __restrict__ erbf, const short* __restrict__ pRbf,
    const short* __restrict__ spass, const short* __restrict__ vold,
    float* __restrict__ s, short* __restrict__ vnew) {
    __shared__ short gate_lds[GEB * GS];
    __shared__ int   src_lds[GEB];
    __shared__ float4 rh_lds[GEB];
    int tid = threadIdx.x;
    int lane = tid & 63;
    int wv = tid >> 6;         // 0 or 1
    int c = tid;               // channel 0..127
    int ntb = wv * 12;         // this wave's n-tile range
    bf16x8 bfr[12];
    #pragma unroll
    for (int t = 0; t < 12; ++t)
        bfr[t] = *(const bf16x8*)(pRbf + ((size_t)((ntb + t) * 64 + lane)) * 8);
    int r0 = (lane >> 4) * 4;
    int fcol = lane & 15;
    for (int n = blockIdx.x; n < N_NODES; n += gridDim.x) {
        int p0 = rowptr[n], p1 = rowptr[n + 1];
        float sa = 0.f, va0 = 0.f, va1 = 0.f, va2 = 0.f;
        for (int pb = p0; pb < p1; pb += GEB) {
            int erow = pb + (lane & 15);
            if (erow >= p1) erow = p1 - 1;
            bf16x8 afrag = *(const bf16x8*)(erbf + (size_t)erow * 32 + (lane >> 4) * 8);
            if (tid < GEB) {
                int p = pb + tid;
                if (p < p1) {
                    src_lds[tid] = esrc[p];
                    const short* eb = erbf + (size_t)p * 32;
                    rh_lds[tid] = make_float4(bf2f(eb[21]), bf2f(eb[22]), bf2f(eb[23]), 0.f);
                }
            }
            #pragma unroll
            for (int t = 0; t < 12; ++t) {
                f32x4 acc = {0.f, 0.f, 0.f, 0.f};
                acc = __builtin_amdgcn_mfma_f32_16x16x32_bf16(afrag, bfr[t], acc, 0, 0, 0);
                int col = (ntb + t) * 16 + fcol;
                int oidx = (col < 256) ? (((col & 127) << 1) | (col >> 7)) : col;
                #pragma unroll
                for (int j = 0; j < 4; ++j)
                    gate_lds[(r0 + j) * GS + oidx] = f2bf(acc[j]);
            }
            __syncthreads();
            int pe = (pb + GEB < p1) ? pb + GEB : p1;
            for (int p = pb; p < pe; ++p) {
                int src = src_lds[p - pb];
                float4 rh = rh_lds[p - pb];
                const short* g = gate_lds + (p - pb) * GS;
                unsigned gp = *(const unsigned*)(g + 2 * c);
                float a0 = bf2f((short)(gp & 0xFFFF));
                float a1 = bf2f((short)(gp >> 16));
                float a2 = bf2f(g[256 + c]);
                const short* sp = spass + (size_t)src * D3;
                unsigned spp = *(const unsigned*)(sp + 2 * c);
                float dv = a0 * bf2f((short)(spp & 0xFFFF));
                float ds = a1 * bf2f((short)(spp >> 16));
                float dr = a2 * bf2f(sp[256 + c]);
                sa += ds;
                const short* vs = vold + (size_t)src * D3;
                va0 += bf2f(vs[c]) * dv + rh.x * dr;
                va1 += bf2f(vs[128 + c]) * dv + rh.y * dr;
                va2 += bf2f(vs[256 + c]) * dv + rh.z * dr;
            }
            __syncthreads();
        }
        s[(size_t)n * D + c] += sa;
        size_t vb = (size_t)n * D3;
        vnew[vb + c]       = f2bf(bf2f(vold[vb + c]) + va0);
        vnew[vb + 128 + c] = f2bf(bf2f(vold[vb + 128 + c]) + va1);
        vnew[vb + 256 + c] = f2bf(bf2f(vold[vb + 256 + c]) + va2);
    }
}

// ---------------- readout ----------------
__global__ void k_blue_dot(const short* __restrict__ h, const int* __restrict__ graph_idx,
                           const float* __restrict__ w2, const float* __restrict__ b2,
                           float* __restrict__ out) {
    __shared__ float red[4];
    int c = threadIdx.x & 127;
    int n = blockIdx.x * 2 + (threadIdx.x >> 7);
    float val = bf2f(h[(size_t)n * D + c]) * w2[c];
    #pragma unroll
    for (int off = 32; off > 0; off >>= 1) val += __shfl_down(val, off, 64);
    if ((threadIdx.x & 63) == 0) red[threadIdx.x >> 6] = val;
    __syncthreads();
    if (threadIdx.x == 0)   atomicAdd(&out[graph_idx[n]], red[0] + red[1] + b2[0]);
    if (threadIdx.x == 128) atomicAdd(&out[graph_idx[n]], red[2] + red[3] + b2[0]);
}

static inline int gemm_grid(int M) { return (M / 16 + 3) / 4; }

extern "C" void kernel_launch(void* const* d_in, const int* in_sizes, int n_in,
                              void* d_out, int out_size, void* d_ws, size_t ws_size,
                              hipStream_t stream) {
    const int*   z         = (const int*)d_in[0];
    const int*   edges     = (const int*)d_in[1];
    const float* r_ij      = (const float*)d_in[2];
    const float* rhat      = (const float*)d_in[3];
    const int*   graph_idx = (const int*)d_in[4];
    const float* emb       = (const float*)d_in[5];
    const float* msg_w1    = (const float*)d_in[6];
    const float* msg_b1    = (const float*)d_in[7];
    const float* msg_w2    = (const float*)d_in[8];
    const float* msg_b2    = (const float*)d_in[9];
    const float* rbf_w     = (const float*)d_in[10];
    const float* rbf_b     = (const float*)d_in[11];
    const float* upd_U     = (const float*)d_in[12];
    const float* upd_V     = (const float*)d_in[13];
    const float* upd_w1    = (const float*)d_in[14];
    const float* upd_b1    = (const float*)d_in[15];
    const float* upd_w2    = (const float*)d_in[16];
    const float* upd_b2    = (const float*)d_in[17];
    const float* blue_w1   = (const float*)d_in[18];
    const float* blue_b1   = (const float*)d_in[19];
    const float* blue_w2   = (const float*)d_in[20];
    const float* blue_b2   = (const float*)d_in[21];
    float* out = (float*)d_out;

    char* ws = (char*)d_ws;
    size_t off = 0;
    auto alloc = [&](size_t bytes) { void* p = ws + off; off += (bytes + 255) & ~(size_t)255; return p; };

    float* s      = (float*)alloc((size_t)N_NODES * D * 4);            // 25.6 MB
    short* bufV0  = (short*)alloc((size_t)N_NODES * D3 * 2);           // 38.4 MB (v state / Uv scratch)
    short* bufV1  = (short*)alloc((size_t)N_NODES * D3 * 2);           // 38.4 MB
    short* spassI = (short*)alloc((size_t)N_NODES * D3 * 2);           // 38.4 MB (pair-interleaved s_pass)
    short* hbuf   = (short*)alloc((size_t)N_NODES * D * 2);            // 12.8 MB
    short* Vv     = (short*)alloc((size_t)N_NODES * D3 * 2);           // 38.4 MB
    // edge tables
    int*    esrc   = (int*)alloc((size_t)N_EDGES * 4);                 // 1.6 MB
    short*  erbf   = (short*)alloc((size_t)N_EDGES * 32 * 2);          // 25.6 MB
    int*    rowptr = (int*)alloc((size_t)(N_NODES + 1) * 4);
    int*    cnt    = (int*)alloc((size_t)N_NODES * 4);                 // hist then cursor
    int*    csum   = (int*)alloc(NCH * 4);
    int*    cbase  = (int*)alloc(NCH * 4);

    // packed weights
    short* pBlue = (short*)alloc(16384 * 2);
    short* pRbfAll = (short*)alloc((size_t)3 * 12288 * 2);
    short* pMsgW1[3]; short* pMsgW2[3]; short* pUV[3]; short* pUpdW1[3]; short* pUpdW2[3];
    for (int i = 0; i < 3; ++i) {
        pMsgW1[i] = (short*)alloc(16384 * 2);
        pMsgW2[i] = (short*)alloc(49152 * 2);
        pUV[i]    = (short*)alloc(32768 * 2);   // U tiles then V tiles
        pUpdW1[i] = (short*)alloc(32768 * 2);
        pUpdW2[i] = (short*)alloc(49152 * 2);
    }

    // ---- all GEMM-weight packs in one dispatch ----
    PackJobs jobs;
    jobs.njobs = 0;
    int bacc = 0;
    auto addjob = [&](const float* W, short* P, int K, int N) {
        int j = jobs.njobs++;
        jobs.W[j] = W; jobs.P[j] = P; jobs.K[j] = K; jobs.N[j] = N;
        jobs.boff[j] = bacc;
        int total = (N / 16) * (K / 32) * 64;
        bacc += (total + 255) / 256;
        jobs.boff[j + 1] = bacc;
    };
    addjob(blue_w1, pBlue, 128, 128);
    for (int i = 0; i < 3; ++i) {
        addjob(msg_w1 + (size_t)i * D * D,     pMsgW1[i], 128, 128);
        addjob(msg_w2 + (size_t)i * D * D3,    pMsgW2[i], 128, 384);
        addjob(upd_U  + (size_t)i * D * D,     pUV[i],          128, 128);
        addjob(upd_V  + (size_t)i * D * D,     pUV[i] + 16384,  128, 128);
        addjob(upd_w1 + (size_t)i * 2 * D * D, pUpdW1[i], 256, 128);
        addjob(upd_w2 + (size_t)i * D * D3,    pUpdW2[i], 128, 384);
    }
    k_packall<<<bacc, 256, 0, stream>>>(jobs);
    k_packrbf<<<18, 256, 0, stream>>>(rbf_w, rbf_b, pRbfAll);

    // ---- edge sort precompute (once per launch) ----
    hipMemsetAsync(cnt, 0, (size_t)N_NODES * 4, stream);
    k_hist<<<(N_EDGES + 255) / 256, 256, 0, stream>>>(edges, cnt);
    k_scan1<<<NCH, 512, 0, stream>>>(cnt, csum);
    k_scan2<<<1, 64, 0, stream>>>(csum, cbase);
    k_scan3<<<NCH, 512, 0, stream>>>(cnt, cbase, rowptr);
    hipMemsetAsync(cnt, 0, (size_t)N_NODES * 4, stream);  // reuse as cursor
    k_scatter<<<(N_EDGES + 255) / 256, 256, 0, stream>>>(edges, r_ij, rhat, rowptr, cnt,
                                                         esrc, erbf);

    // ---- state init ----
    hipMemsetAsync(bufV0, 0, (size_t)N_NODES * D3 * 2, stream);
    hipMemsetAsync(d_out, 0, (size_t)out_size * sizeof(float), stream);
    k_embed<<<(N_NODES * D) / 256, 256, 0, stream>>>(z, emb, s);

    const int gN  = gemm_grid(N_NODES);
    const int gN3 = gemm_grid(N_NODES * 3);

    for (int i = 0; i < 3; ++i) {
        short* vstate = (i & 1) ? bufV1 : bufV0;   // current v (bf16)
        short* vscr   = (i & 1) ? bufV0 : bufV1;   // next v
        // h = silu(s @ msg_w1 + b1)
        k_gemm<128, 128, true, 1, 0><<<gN, 256, 0, stream>>>(
            s, nullptr, pMsgW1[i], msg_b1 + (size_t)i * D, hbuf, N_NODES);
        // s_pass (pair-interleaved) = h @ msg_w2 + b2
        k_gemm<128, 384, false, 0, 1><<<gN, 256, 0, stream>>>(
            hbuf, nullptr, pMsgW2[i], msg_b2 + (size_t)i * D3, spassI, N_NODES);
        // segment-sum edge gather with MFMA gates: s += ds ; vscr = vstate + dv
        k_edge3<<<6144, 128, 0, stream>>>(rowptr, esrc, erbf,
                                          pRbfAll + (size_t)i * 12288,
                                          spassI, vstate, s, vscr);
        // Uv (into dead vstate buffer) and Vv in ONE GEMM (single A read)
        k_gemmUV<<<gN3, 256, 0, stream>>>(vscr, pUV[i], vstate, Vv, N_NODES * 3);
        // h2 = silu([Vnorm(Vv) | s] @ upd_w1 + b1)   (V_norm fused into A-load)
        k_gemm<256, 128, true, 3, 0><<<gN, 256, 0, stream>>>(
            Vv, s, pUpdW1[i], upd_b1 + (size_t)i * D, hbuf, N_NODES);
        // a = h2 @ upd_w2 + b2 fused with gated apply of s and v (in place on vscr)
        k_w2apply<<<gN, 256, 0, stream>>>(hbuf, pUpdW2[i], upd_b2 + (size_t)i * D3,
                                          vstate, Vv, s, vscr, N_NODES);
    }

    // readout
    k_gemm<128, 128, true, 1, 0><<<gN, 256, 0, stream>>>(
        s, nullptr, pBlue, blue_b1, hbuf, N_NODES);
    k_blue_dot<<<N_NODES / 2, 256, 0, stream>>>(hbuf, graph_idx, blue_w2, blue_b2, out);
}

// Round 8
// 1000.712 us; speedup vs baseline: 1.2198x; 1.2198x over previous
//
#include <hip/hip_runtime.h>
#include <hip/hip_bf16.h>
#include <math.h>

#define N_NODES 50000
#define N_EDGES 400000
#define N_GRAPHS 2500
#define D 128
#define D3 384
#define N_RBF 20
#define R_CUT 5.0f
#define PI_F 3.14159265358979f
#define NCH 98   // ceil(50000/512)
#define GEB 16   // gate edge batch (one MFMA row-block)
#define GLDS_STRIDE 388  // pad: 776 B row stride -> disjoint bank windows

typedef __attribute__((ext_vector_type(8))) short bf16x8;
typedef __attribute__((ext_vector_type(4))) float f32x4;

__device__ __forceinline__ float silu_f(float x) {
    return x / (1.0f + __expf(-x));
}
__device__ __forceinline__ short f2bf(float x) {
    union { float f; unsigned u; } v; v.f = x;
    unsigned r = (v.u + 0x7FFFu + ((v.u >> 16) & 1u)) >> 16;
    return (short)r;
}
__device__ __forceinline__ float bf2f(short x) {
    union { unsigned u; float f; } v; v.u = ((unsigned)(unsigned short)x) << 16;
    return v.f;
}

// ---------------- all weight packs in ONE dispatch ----------------
#define MAXJOBS 19
struct PackJobs {
    const float* W[MAXJOBS];
    short* P[MAXJOBS];
    int K[MAXJOBS];
    int N[MAXJOBS];
    int boff[MAXJOBS + 1];
    int njobs;
};
__global__ void k_packall(PackJobs jobs) {
    int b = blockIdx.x;
    int j = 0;
    while (j + 1 < jobs.njobs && b >= jobs.boff[j + 1]) ++j;
    int t = (b - jobs.boff[j]) * 256 + threadIdx.x;
    int K = jobs.K[j], N = jobs.N[j];
    int NKT = K / 32;
    int total = (N / 16) * NKT * 64;
    if (t >= total) return;
    const float* W = jobs.W[j];
    short* P = jobs.P[j];
    int lane = t & 63;
    int kt = (t >> 6) % NKT;
    int nt = (t >> 6) / NKT;
    int k0 = kt * 32 + (lane >> 4) * 8;
    int col = nt * 16 + (lane & 15);
    #pragma unroll
    for (int q = 0; q < 8; ++q)
        P[(size_t)t * 8 + q] = f2bf(W[(size_t)(k0 + q) * N + col]);
}

// pack [rbf_w(20 rows); rbf_b(1 row); zeros] -> frags, 3 blocks in one dispatch
__global__ void k_packrbf(const float* __restrict__ rbf_w, const float* __restrict__ rbf_b,
                          short* __restrict__ P) {
    int t = blockIdx.x * 256 + threadIdx.x;
    if (t >= 3 * 1536) return;
    int i = t / 1536;
    int r = t - i * 1536;        // nt*64 + lane
    int lane = r & 63;
    int nt = r >> 6;
    int col = nt * 16 + (lane & 15);
    int k0 = (lane >> 4) * 8;
    const float* W = rbf_w + (size_t)i * N_RBF * D3;
    const float* B = rbf_b + (size_t)i * D3;
    short* out = P + (size_t)i * 12288 + (size_t)r * 8;
    #pragma unroll
    for (int q = 0; q < 8; ++q) {
        int k = k0 + q;
        float v = (k < N_RBF) ? W[(size_t)k * D3 + col] : ((k == N_RBF) ? B[col] : 0.0f);
        out[q] = f2bf(v);
    }
}

// ---------------- generic MFMA GEMM, 32-row tile per wave ----------------
// AMODE: 0 = A bf16 ; 1 = A f32 ; 2 = split A1 bf16 (k<128) + A2 f32 (k>=128)
template<int K, int N, bool SILU, int AMODE>
__global__ __launch_bounds__(256) void k_gemm(const void* __restrict__ Aptr,
                                              const void* __restrict__ A2ptr,
                                              const short* __restrict__ Bp,
                                              const float* __restrict__ bias,
                                              short* __restrict__ Cbf, int M) {
    constexpr int NKT = K / 32, NNT = N / 16;
    int lane = threadIdx.x & 63, wv = threadIdx.x >> 6;
    int tile = blockIdx.x * 4 + wv;
    int base = tile * 32;
    if (base >= M) return;
    bool has2 = (base + 16 < M);
    int r16 = lane & 15;
    int kgrp = (lane >> 4) * 8;
    int arow0 = base + r16;
    int arow1 = has2 ? (base + 16 + r16) : arow0;

    bf16x8 a0[NKT], a1[NKT];
    #pragma unroll
    for (int ss = 0; ss < 2; ++ss) {
        int arow = ss ? arow1 : arow0;
        bf16x8* a = ss ? a1 : a0;
        if (AMODE == 0) {
            const short* A = (const short*)Aptr + (size_t)arow * K + kgrp;
            #pragma unroll
            for (int kt = 0; kt < NKT; ++kt) a[kt] = *(const bf16x8*)(A + kt * 32);
        } else if (AMODE == 1) {
            const float* A = (const float*)Aptr + (size_t)arow * K + kgrp;
            #pragma unroll
            for (int kt = 0; kt < NKT; ++kt)
                #pragma unroll
                for (int j = 0; j < 8; ++j) a[kt][j] = f2bf(A[kt * 32 + j]);
        } else {
            const short* A1 = (const short*)Aptr + (size_t)arow * 128 + kgrp;
            const float* A2 = (const float*)A2ptr + (size_t)arow * 128 + kgrp;
            #pragma unroll
            for (int kt = 0; kt < 4 && kt < NKT; ++kt) a[kt] = *(const bf16x8*)(A1 + kt * 32);
            #pragma unroll
            for (int kt = 4; kt < NKT; ++kt)
                #pragma unroll
                for (int j = 0; j < 8; ++j) a[kt][j] = f2bf(A2[(kt - 4) * 32 + j]);
        }
    }

    int crow0 = base + (lane >> 4) * 4;
    int ccol = lane & 15;
    const bf16x8* Bv = (const bf16x8*)Bp;
    #pragma unroll
    for (int nt = 0; nt < NNT; ++nt) {
        f32x4 acc0 = {0.f, 0.f, 0.f, 0.f};
        f32x4 acc1 = {0.f, 0.f, 0.f, 0.f};
        #pragma unroll
        for (int kt = 0; kt < NKT; ++kt) {
            bf16x8 b = Bv[(nt * NKT + kt) * 64 + lane];
            acc0 = __builtin_amdgcn_mfma_f32_16x16x32_bf16(a0[kt], b, acc0, 0, 0, 0);
            acc1 = __builtin_amdgcn_mfma_f32_16x16x32_bf16(a1[kt], b, acc1, 0, 0, 0);
        }
        int col = nt * 16 + ccol;
        float bs = bias ? bias[col] : 0.0f;
        #pragma unroll
        for (int j = 0; j < 4; ++j) {
            float v = acc0[j] + bs;
            if (SILU) v = silu_f(v);
            Cbf[(size_t)(crow0 + j) * N + col] = f2bf(v);
        }
        if (has2) {
            #pragma unroll
            for (int j = 0; j < 4; ++j) {
                float v = acc1[j] + bs;
                if (SILU) v = silu_f(v);
                Cbf[(size_t)(crow0 + 16 + j) * N + col] = f2bf(v);
            }
        }
    }
}

// ---------------- fused U/V GEMM (32-row tile): one A read, two C outputs ----------------
__global__ __launch_bounds__(256) void k_gemmUV(const short* __restrict__ A,
                                                const short* __restrict__ Bp,
                                                short* __restrict__ Cu,
                                                short* __restrict__ Cv, int M) {
    int lane = threadIdx.x & 63, wv = threadIdx.x >> 6;
    int tile = blockIdx.x * 4 + wv;
    int base = tile * 32;
    if (base >= M) return;
    bool has2 = (base + 16 < M);
    int r16 = lane & 15;
    int kgrp = (lane >> 4) * 8;
    const short* Ar0 = A + (size_t)(base + r16) * 128 + kgrp;
    const short* Ar1 = A + (size_t)((has2 ? base + 16 : base) + r16) * 128 + kgrp;
    bf16x8 a0[4], a1[4];
    #pragma unroll
    for (int kt = 0; kt < 4; ++kt) {
        a0[kt] = *(const bf16x8*)(Ar0 + kt * 32);
        a1[kt] = *(const bf16x8*)(Ar1 + kt * 32);
    }
    int crow0 = base + (lane >> 4) * 4;
    int ccol = lane & 15;
    const bf16x8* Bv = (const bf16x8*)Bp;
    #pragma unroll
    for (int nt = 0; nt < 16; ++nt) {
        f32x4 acc0 = {0.f, 0.f, 0.f, 0.f};
        f32x4 acc1 = {0.f, 0.f, 0.f, 0.f};
        #pragma unroll
        for (int kt = 0; kt < 4; ++kt) {
            bf16x8 b = Bv[(nt * 4 + kt) * 64 + lane];
            acc0 = __builtin_amdgcn_mfma_f32_16x16x32_bf16(a0[kt], b, acc0, 0, 0, 0);
            acc1 = __builtin_amdgcn_mfma_f32_16x16x32_bf16(a1[kt], b, acc1, 0, 0, 0);
        }
        int col = nt * 16 + ccol;
        short* C = (col < 128) ? Cu : Cv;
        int cc = col & 127;
        #pragma unroll
        for (int j = 0; j < 4; ++j)
            C[(size_t)(crow0 + j) * 128 + cc] = f2bf(acc0[j]);
        if (has2) {
            #pragma unroll
            for (int j = 0; j < 4; ++j)
                C[(size_t)(crow0 + 16 + j) * 128 + cc] = f2bf(acc1[j]);
        }
    }
}

// ---------------- embed ----------------
__global__ void k_embed(const int* __restrict__ z, const float* __restrict__ emb,
                        float* __restrict__ s) {
    int i = blockIdx.x * blockDim.x + threadIdx.x;
    if (i < N_NODES * D) {
        int n = i >> 7, c = i & 127;
        s[i] = emb[z[n] * D + c];
    }
}

// ---------------- edge-sort precompute ----------------
__global__ void k_hist(const int* __restrict__ edges, int* __restrict__ cnt) {
    int e = blockIdx.x * 256 + threadIdx.x;
    if (e < N_EDGES) atomicAdd(&cnt[edges[2 * e]], 1);
}

__global__ void k_scan1(const int* __restrict__ cnt, int* __restrict__ csum) {
    int t = threadIdx.x;                  // 512 threads
    int g = blockIdx.x * 512 + t;
    int v = (g < N_NODES) ? cnt[g] : 0;
    #pragma unroll
    for (int off = 32; off > 0; off >>= 1) v += __shfl_down(v, off, 64);
    __shared__ int ws[8];
    if ((t & 63) == 0) ws[t >> 6] = v;
    __syncthreads();
    if (t == 0) {
        int sum = 0;
        #pragma unroll
        for (int i = 0; i < 8; ++i) sum += ws[i];
        csum[blockIdx.x] = sum;
    }
}

__global__ void k_scan2(const int* __restrict__ csum, int* __restrict__ cbase) {
    if (threadIdx.x == 0 && blockIdx.x == 0) {
        int s = 0;
        for (int i = 0; i < NCH; ++i) { cbase[i] = s; s += csum[i]; }
    }
}

__global__ void k_scan3(const int* __restrict__ cnt, const int* __restrict__ cbase,
                        int* __restrict__ rowptr) {
    __shared__ int buf[512];
    int t = threadIdx.x;
    int g = blockIdx.x * 512 + t;
    int orig = (g < N_NODES) ? cnt[g] : 0;
    buf[t] = orig;
    __syncthreads();
    for (int off = 1; off < 512; off <<= 1) {
        int v = (t >= off) ? buf[t - off] : 0;
        __syncthreads();
        buf[t] += v;
        __syncthreads();
    }
    if (g < N_NODES) rowptr[g] = cbase[blockIdx.x] + buf[t] - orig;
    if (g == 0 && blockIdx.x == 0) rowptr[N_NODES] = N_EDGES;
}

// scatter edges into dst-sorted order; per edge: erbf[32] bf16 (rbf*fc, fc, 0...), rhat float4
__global__ void k_scatter(const int* __restrict__ edges, const float* __restrict__ r_ij,
                          const float* __restrict__ rhat, const int* __restrict__ rowptr,
                          int* __restrict__ cursor, int* __restrict__ esrc,
                          short* __restrict__ erbf, float4* __restrict__ erhat) {
    int e = blockIdx.x * 256 + threadIdx.x;
    if (e >= N_EDGES) return;
    int dst = edges[2 * e], src = edges[2 * e + 1];
    int p = rowptr[dst] + atomicAdd(&cursor[dst], 1);
    esrc[p] = src;
    float r = r_ij[e];
    float fc = (r <= R_CUT) ? 0.5f * (cosf(PI_F * r / R_CUT) + 1.0f) : 0.0f;
    float inv_r = 1.0f / r;
    short rec[32];
    #pragma unroll
    for (int k = 0; k < N_RBF; ++k)
        rec[k] = f2bf(sinf((float)(k + 1) * (PI_F / R_CUT) * r) * inv_r * fc);
    rec[20] = f2bf(fc);
    #pragma unroll
    for (int k = 21; k < 32; ++k) rec[k] = 0;
    short* out = erbf + (size_t)p * 32;
    #pragma unroll
    for (int k = 0; k < 32; ++k) out[k] = rec[k];
    float4 rh;
    rh.x = rhat[3 * e]; rh.y = rhat[3 * e + 1]; rh.z = rhat[3 * e + 2]; rh.w = 0.f;
    erhat[p] = rh;
}

// ---------------- edge kernel: MFMA gates + gather, one node per 128-thread block ----------------
// HASV=false (block 0): v==0, skip all vold gathers and the d_v path.
template<bool HASV>
__global__ __launch_bounds__(128, 4) void k_edge3(
    const int* __restrict__ rowptr, const int* __restrict__ esrc,
    const short* __restrict__ erbf, const float4* __restrict__ erhat,
    const short* __restrict__ pRbf,
    const short* __restrict__ spass, const short* __restrict__ vold,
    float* __restrict__ s, short* __restrict__ vnew) {
    __shared__ short gate_lds[GEB * GLDS_STRIDE];
    __shared__ int   src_lds[GEB];
    __shared__ float4 rh_lds[GEB];
    int tid = threadIdx.x;
    int lane = tid & 63;
    int wv = tid >> 6;         // 0 or 1
    int c = tid;               // channel 0..127
    int ntb = wv * 12;         // this wave's n-tile range
    bf16x8 bfr[12];
    #pragma unroll
    for (int t = 0; t < 12; ++t)
        bfr[t] = *(const bf16x8*)(pRbf + ((size_t)((ntb + t) * 64 + lane)) * 8);
    int r0 = (lane >> 4) * 4;
    int fcol = lane & 15;
    for (int n = blockIdx.x; n < N_NODES; n += gridDim.x) {
        int p0 = rowptr[n], p1 = rowptr[n + 1];
        float sa = 0.f, va0 = 0.f, va1 = 0.f, va2 = 0.f;
        for (int pb = p0; pb < p1; pb += GEB) {
            int erow = pb + (lane & 15);
            if (erow >= p1) erow = p1 - 1;
            bf16x8 afrag = *(const bf16x8*)(erbf + (size_t)erow * 32 + (lane >> 4) * 8);
            if (tid < GEB) {
                int p = pb + tid;
                if (p < p1) { src_lds[tid] = esrc[p]; rh_lds[tid] = erhat[p]; }
            }
            #pragma unroll
            for (int t = 0; t < 12; ++t) {
                f32x4 acc = {0.f, 0.f, 0.f, 0.f};
                acc = __builtin_amdgcn_mfma_f32_16x16x32_bf16(afrag, bfr[t], acc, 0, 0, 0);
                int col = (ntb + t) * 16 + fcol;
                #pragma unroll
                for (int j = 0; j < 4; ++j)
                    gate_lds[(r0 + j) * GLDS_STRIDE + col] = f2bf(acc[j]);
            }
            __syncthreads();
            int pe = (pb + GEB < p1) ? pb + GEB : p1;
            for (int p = pb; p < pe; ++p) {
                int src = src_lds[p - pb];
                float4 rh = rh_lds[p - pb];
                const short* g = gate_lds + (p - pb) * GLDS_STRIDE;
                float a1 = bf2f(g[128 + c]);
                float a2 = bf2f(g[256 + c]);
                const short* sp = spass + (size_t)src * D3;
                float ds = a1 * bf2f(sp[128 + c]);
                float dr = a2 * bf2f(sp[256 + c]);
                sa += ds;
                if (HASV) {
                    float a0 = bf2f(g[c]);
                    float dv = a0 * bf2f(sp[c]);
                    const short* vs = vold + (size_t)src * D3;
                    va0 += bf2f(vs[c]) * dv + rh.x * dr;
                    va1 += bf2f(vs[128 + c]) * dv + rh.y * dr;
                    va2 += bf2f(vs[256 + c]) * dv + rh.z * dr;
                } else {
                    va0 += rh.x * dr;
                    va1 += rh.y * dr;
                    va2 += rh.z * dr;
                }
            }
            __syncthreads();
        }
        s[(size_t)n * D + c] += sa;
        size_t vb = (size_t)n * D3;
        if (HASV) {
            vnew[vb + c]       = f2bf(bf2f(vold[vb + c]) + va0);
            vnew[vb + 128 + c] = f2bf(bf2f(vold[vb + 128 + c]) + va1);
            vnew[vb + 256 + c] = f2bf(bf2f(vold[vb + 256 + c]) + va2);
        } else {
            vnew[vb + c]       = f2bf(va0);
            vnew[vb + 128 + c] = f2bf(va1);
            vnew[vb + 256 + c] = f2bf(va2);
        }
    }
}

// ---------------- V_norm ----------------
__global__ void k_svbuild(const short* __restrict__ Vv, short* __restrict__ Vn) {
    int i = blockIdx.x * 256 + threadIdx.x;   // over N_NODES*D
    int n = i >> 7, c = i & 127;
    float acc = 0.f;
    #pragma unroll
    for (int d = 0; d < 3; ++d) {
        float v = bf2f(Vv[(size_t)(n * 3 + d) * D + c]);
        acc += v * v;
    }
    Vn[i] = f2bf(sqrtf(acc));
}

// ---------------- apply gated update (v state in place, bf16) ----------------
__global__ void k_apply(float* __restrict__ s, short* __restrict__ v,
                        const short* __restrict__ Uv, const short* __restrict__ Vv,
                        const short* __restrict__ a_bf) {
    int i = blockIdx.x * 256 + threadIdx.x;   // over N_NODES*D
    int n = i >> 7, c = i & 127;
    float avv = bf2f(a_bf[(size_t)n * D3 + c]);
    float asv = bf2f(a_bf[(size_t)n * D3 + 128 + c]);
    float ass = bf2f(a_bf[(size_t)n * D3 + 256 + c]);
    float scal = 0.f;
    float uvr[3];
    #pragma unroll
    for (int d = 0; d < 3; ++d) {
        float u = bf2f(Uv[(size_t)(n * 3 + d) * D + c]);
        float vv = bf2f(Vv[(size_t)(n * 3 + d) * D + c]);
        uvr[d] = u;
        scal += u * vv;
    }
    s[i] += scal * asv + ass;
    #pragma unroll
    for (int d = 0; d < 3; ++d) {
        size_t idx = (size_t)n * D3 + d * 128 + c;
        v[idx] = f2bf(bf2f(v[idx]) + avv * uvr[d]);
    }
}

// ---------------- readout ----------------
__global__ void k_blue_dot(const short* __restrict__ h, const int* __restrict__ graph_idx,
                           const float* __restrict__ w2, const float* __restrict__ b2,
                           float* __restrict__ out) {
    __shared__ float red[4];
    int c = threadIdx.x & 127;
    int n = blockIdx.x * 2 + (threadIdx.x >> 7);
    float val = bf2f(h[(size_t)n * D + c]) * w2[c];
    #pragma unroll
    for (int off = 32; off > 0; off >>= 1) val += __shfl_down(val, off, 64);
    if ((threadIdx.x & 63) == 0) red[threadIdx.x >> 6] = val;
    __syncthreads();
    if (threadIdx.x == 0)   atomicAdd(&out[graph_idx[n]], red[0] + red[1] + b2[0]);
    if (threadIdx.x == 128) atomicAdd(&out[graph_idx[n]], red[2] + red[3] + b2[0]);
}

static inline int g32(int M) { int t = (M + 31) / 32; return (t + 3) / 4; }

extern "C" void kernel_launch(void* const* d_in, const int* in_sizes, int n_in,
                              void* d_out, int out_size, void* d_ws, size_t ws_size,
                              hipStream_t stream) {
    const int*   z         = (const int*)d_in[0];
    const int*   edges     = (const int*)d_in[1];
    const float* r_ij      = (const float*)d_in[2];
    const float* rhat      = (const float*)d_in[3];
    const int*   graph_idx = (const int*)d_in[4];
    const float* emb       = (const float*)d_in[5];
    const float* msg_w1    = (const float*)d_in[6];
    const float* msg_b1    = (const float*)d_in[7];
    const float* msg_w2    = (const float*)d_in[8];
    const float* msg_b2    = (const float*)d_in[9];
    const float* rbf_w     = (const float*)d_in[10];
    const float* rbf_b     = (const float*)d_in[11];
    const float* upd_U     = (const float*)d_in[12];
    const float* upd_V     = (const float*)d_in[13];
    const float* upd_w1    = (const float*)d_in[14];
    const float* upd_b1    = (const float*)d_in[15];
    const float* upd_w2    = (const float*)d_in[16];
    const float* upd_b2    = (const float*)d_in[17];
    const float* blue_w1   = (const float*)d_in[18];
    const float* blue_b1   = (const float*)d_in[19];
    const float* blue_w2   = (const float*)d_in[20];
    const float* blue_b2   = (const float*)d_in[21];
    float* out = (float*)d_out;

    char* ws = (char*)d_ws;
    size_t off = 0;
    auto alloc = [&](size_t bytes) { void* p = ws + off; off += (bytes + 255) & ~(size_t)255; return p; };

    float* s      = (float*)alloc((size_t)N_NODES * D * 4);            // 25.6 MB
    short* bufV0  = (short*)alloc((size_t)N_NODES * D3 * 2);           // 38.4 MB
    short* bufV1  = (short*)alloc((size_t)N_NODES * D3 * 2);           // 38.4 MB
    short* shrd   = (short*)alloc((size_t)N_NODES * D3 * 2);           // 38.4 MB: s_pass -> Vn -> a
    short* hbuf   = (short*)alloc((size_t)N_NODES * D * 2);            // 12.8 MB
    short* Vv     = (short*)alloc((size_t)N_NODES * D3 * 2);           // 38.4 MB
    short* Vn     = shrd;   // aliases shrd
    // edge tables
    int*    esrc   = (int*)alloc((size_t)N_EDGES * 4);                 // 1.6 MB
    short*  erbf   = (short*)alloc((size_t)N_EDGES * 32 * 2);          // 25.6 MB
    float4* erhat  = (float4*)alloc((size_t)N_EDGES * 16);             // 6.4 MB
    int*    rowptr = (int*)alloc((size_t)(N_NODES + 1) * 4);
    int*    cnt    = (int*)alloc((size_t)N_NODES * 4);                 // hist then cursor
    int*    csum   = (int*)alloc(NCH * 4);
    int*    cbase  = (int*)alloc(NCH * 4);

    // packed weights
    short* pBlue = (short*)alloc(16384 * 2);
    short* pRbfAll = (short*)alloc((size_t)3 * 12288 * 2);
    short* pMsgW1[3]; short* pMsgW2[3]; short* pUV[3]; short* pUpdW1[3]; short* pUpdW2[3];
    for (int i = 0; i < 3; ++i) {
        pMsgW1[i] = (short*)alloc(16384 * 2);
        pMsgW2[i] = (short*)alloc(49152 * 2);
        pUV[i]    = (short*)alloc(32768 * 2);   // U tiles then V tiles
        pUpdW1[i] = (short*)alloc(32768 * 2);
        pUpdW2[i] = (short*)alloc(49152 * 2);
    }

    // ---- all GEMM-weight packs in one dispatch ----
    PackJobs jobs;
    jobs.njobs = 0;
    int bacc = 0;
    auto addjob = [&](const float* W, short* P, int K, int N) {
        int j = jobs.njobs++;
        jobs.W[j] = W; jobs.P[j] = P; jobs.K[j] = K; jobs.N[j] = N;
        jobs.boff[j] = bacc;
        int total = (N / 16) * (K / 32) * 64;
        bacc += (total + 255) / 256;
        jobs.boff[j + 1] = bacc;
    };
    addjob(blue_w1, pBlue, 128, 128);
    for (int i = 0; i < 3; ++i) {
        addjob(msg_w1 + (size_t)i * D * D,     pMsgW1[i], 128, 128);
        addjob(msg_w2 + (size_t)i * D * D3,    pMsgW2[i], 128, 384);
        addjob(upd_U  + (size_t)i * D * D,     pUV[i],          128, 128);
        addjob(upd_V  + (size_t)i * D * D,     pUV[i] + 16384,  128, 128);
        addjob(upd_w1 + (size_t)i * 2 * D * D, pUpdW1[i], 256, 128);
        addjob(upd_w2 + (size_t)i * D * D3,    pUpdW2[i], 128, 384);
    }
    k_packall<<<bacc, 256, 0, stream>>>(jobs);
    k_packrbf<<<18, 256, 0, stream>>>(rbf_w, rbf_b, pRbfAll);

    // ---- edge sort precompute (once per launch) ----
    hipMemsetAsync(cnt, 0, (size_t)N_NODES * 4, stream);
    k_hist<<<(N_EDGES + 255) / 256, 256, 0, stream>>>(edges, cnt);
    k_scan1<<<NCH, 512, 0, stream>>>(cnt, csum);
    k_scan2<<<1, 64, 0, stream>>>(csum, cbase);
    k_scan3<<<NCH, 512, 0, stream>>>(cnt, cbase, rowptr);
    hipMemsetAsync(cnt, 0, (size_t)N_NODES * 4, stream);  // reuse as cursor
    k_scatter<<<(N_EDGES + 255) / 256, 256, 0, stream>>>(edges, r_ij, rhat, rowptr, cnt,
                                                         esrc, erbf, erhat);

    // ---- state init (no bufV0 memset needed: iter0 edge kernel never reads vold) ----
    hipMemsetAsync(d_out, 0, (size_t)out_size * sizeof(float), stream);
    k_embed<<<(N_NODES * D) / 256, 256, 0, stream>>>(z, emb, s);

    const int gN  = g32(N_NODES);
    const int gN3 = g32(N_NODES * 3);

    for (int i = 0; i < 3; ++i) {
        short* vstate = (i & 1) ? bufV1 : bufV0;   // current v (bf16)
        short* vscr   = (i & 1) ? bufV0 : bufV1;   // next v
        // h = silu(s @ msg_w1 + b1)
        k_gemm<128, 128, true, 1><<<gN, 256, 0, stream>>>(
            s, nullptr, pMsgW1[i], msg_b1 + (size_t)i * D, hbuf, N_NODES);
        // s_pass = h @ msg_w2 + b2
        k_gemm<128, 384, false, 0><<<gN, 256, 0, stream>>>(
            hbuf, nullptr, pMsgW2[i], msg_b2 + (size_t)i * D3, shrd, N_NODES);
        // segment-sum edge gather with MFMA gates: s += ds ; vscr = vstate + dv
        if (i == 0)
            k_edge3<false><<<4096, 128, 0, stream>>>(rowptr, esrc, erbf, erhat,
                                                     pRbfAll, shrd, vstate, s, vscr);
        else
            k_edge3<true><<<4096, 128, 0, stream>>>(rowptr, esrc, erbf, erhat,
                                                    pRbfAll + (size_t)i * 12288,
                                                    shrd, vstate, s, vscr);
        // Uv (into dead vstate buffer) and Vv in ONE GEMM (single A read)
        k_gemmUV<<<gN3, 256, 0, stream>>>(vscr, pUV[i], vstate, Vv, N_NODES * 3);
        // V_norm (into shrd; s_pass dead now)
        k_svbuild<<<(N_NODES * D) / 256, 256, 0, stream>>>(Vv, Vn);
        // h2 = silu([Vn | s] @ upd_w1 + b1)
        k_gemm<256, 128, true, 2><<<gN, 256, 0, stream>>>(
            Vn, s, pUpdW1[i], upd_b1 + (size_t)i * D, hbuf, N_NODES);
        // a = h2 @ upd_w2 + b2  (clobbers shrd incl. Vn region — Vn already consumed)
        k_gemm<128, 384, false, 0><<<gN, 256, 0, stream>>>(
            hbuf, nullptr, pUpdW2[i], upd_b2 + (size_t)i * D3, shrd, N_NODES);
        // gated update of s and v (in place on vscr)
        k_apply<<<(N_NODES * D) / 256, 256, 0, stream>>>(s, vscr, vstate, Vv, shrd);
    }

    // readout
    k_gemm<128, 128, true, 1><<<gN, 256, 0, stream>>>(
        s, nullptr, pBlue, blue_b1, hbuf, N_NODES);
    k_blue_dot<<<N_NODES / 2, 256, 0, stream>>>(hbuf, graph_idx, blue_w2, blue_b2, out);
}